// Round 10
// baseline (584.996 us; speedup 1.0000x reference)
//
#include <hip/hip_runtime.h>
#include <hip/hip_bf16.h>
#include <math.h>

typedef unsigned short u16;
typedef unsigned int   u32;
using bf16x8 = __attribute__((ext_vector_type(8))) short;   // 8 bf16 (4 VGPRs)
using f32x4  = __attribute__((ext_vector_type(4))) float;   // MFMA C/D frag

#define TE 256
#define TH 8
#define TS 2048
#define TB 4
#define NTOK 8192
#define NBLK 512                 // persistent grid: 2 blocks/CU guaranteed
// (1/sqrt(32)) * log2(e): folded into Q so softmax is pure exp2
#define QSCALE 0.2550120651552454f
#define EXP2(x) __builtin_amdgcn_exp2f(x)

// pack 2 floats -> 2 bf16 (round-half-up): 2 adds + v_perm
__device__ __forceinline__ u32 pkbf(float a, float b) {
    u32 ua = __float_as_uint(a) + 0x8000u;
    u32 ub = __float_as_uint(b) + 0x8000u;
    return __builtin_amdgcn_perm(ub, ua, 0x07060302u);
}

// ---- hand-rolled grid barrier (sense-reversal, device/agent scope) --------
// Agent-scope acq_rel atomics emit the L2 writeback/invalidate required for
// cross-XCD visibility (per-XCD L2s are non-coherent). Bounded spin: if
// co-residency ever failed, we bail (wrong answer) instead of hanging.
__device__ __forceinline__ void gsync(u32* cnt, u32* gen) {
    __syncthreads();
    if (threadIdx.x == 0) {
        u32 g = __hip_atomic_load(gen, __ATOMIC_RELAXED, __HIP_MEMORY_SCOPE_AGENT);
        u32 a = __hip_atomic_fetch_add(cnt, 1u, __ATOMIC_ACQ_REL, __HIP_MEMORY_SCOPE_AGENT);
        if (a == NBLK - 1) {
            __hip_atomic_store(cnt, 0u, __ATOMIC_RELAXED, __HIP_MEMORY_SCOPE_AGENT);
            __hip_atomic_fetch_add(gen, 1u, __ATOMIC_ACQ_REL, __HIP_MEMORY_SCOPE_AGENT);
        } else {
            u32 spins = 0;
            while (__hip_atomic_load(gen, __ATOMIC_ACQUIRE, __HIP_MEMORY_SCOPE_AGENT) == g) {
                if (++spins > (1u << 22)) break;
            }
        }
    }
    __syncthreads();
}

// ---------------- LayerNorm phase: 8 rows per vblock (2 per wave) ----------
__device__ __forceinline__ void ln_phase(int vb, const float* __restrict__ in,
        u16* __restrict__ out, const float* __restrict__ gamma,
        const float* __restrict__ beta) {
    const int w = threadIdx.x >> 6, lane = threadIdx.x & 63;
    #pragma unroll
    for (int r = 0; r < 2; r++) {
        int row = vb * 8 + w * 2 + r;
        float4 v = ((const float4*)(in + (size_t)row * TE))[lane];
        float s  = v.x + v.y + v.z + v.w;
        float s2 = v.x*v.x + v.y*v.y + v.z*v.z + v.w*v.w;
        #pragma unroll
        for (int off = 32; off > 0; off >>= 1) {
            s  += __shfl_down(s,  off, 64);
            s2 += __shfl_down(s2, off, 64);
        }
        s  = __shfl(s,  0, 64);
        s2 = __shfl(s2, 0, 64);
        float mu = s * (1.f / TE);
        float rs = rsqrtf(s2 * (1.f / TE) - mu * mu + 1e-5f);
        float4 g = ((const float4*)gamma)[lane];
        float4 b = ((const float4*)beta )[lane];
        u32 lo = pkbf((v.x - mu) * rs * g.x + b.x, (v.y - mu) * rs * g.y + b.y);
        u32 hi = pkbf((v.z - mu) * rs * g.z + b.z, (v.w - mu) * rs * g.w + b.w);
        ((uint2*)(out + (size_t)row * TE))[lane] = make_uint2(lo, hi);
    }
}

// -------------- weight fp32->bf16 conversion (768 vblocks) -----------------
__device__ __forceinline__ void conv_phase(int vb, const float* __restrict__ s0,
        u16* d0, const float* __restrict__ s1, u16* d1,
        const float* __restrict__ s2, u16* d2, const float* __restrict__ s3,
        u16* d3) {
    int i = (vb * 256 + threadIdx.x) * 4;
    if (i < 786432) {
        const float* s; u16* d;
        if      (i < 196608) { s = s0; d = d0; }
        else if (i < 262144) { s = s1; d = d1; i -= 196608; }
        else if (i < 524288) { s = s2; d = d2; i -= 262144; }
        else                 { s = s3; d = d3; i -= 524288; }
        float4 v = *(const float4*)(s + i);
        *(uint2*)(d + i) = make_uint2(pkbf(v.x, v.y), pkbf(v.z, v.w));
    }
}

// ---------- weight-stationary GEMM phase: C[tok][feat] = A @ W^T -----------
// 4 waves share one W feat-slice in LDS (<=512-k chunks; K-loop barrier-free;
// A frags direct from global in B-operand layout, double-buffered). NT=2:
// each wave 32 tokens, 128 tok/vblock. vb mapping: fslice = vb % NSLICE,
// tokgrp = vb / NSLICE. Unconditional sync before staging (safe for
// back-to-back vb iterations in the persistent loop).
// EPI: 0 = bf16 +qscale(feat<256); 1 = fp32 + residual R;
//      2 = bf16 relu(acc+bias); 3 = fp32 acc + bias + Cf (in-place residual).
template<int K, int NFEAT, int NF, int NSLICE, int EPI>
__device__ __forceinline__ void wgemm_phase(u16* Wl, int vb,
        const u16* __restrict__ A, const u16* __restrict__ W,
        const float* __restrict__ bias, const float* __restrict__ R,
        float* __restrict__ Cf, u16* __restrict__ Cb, int M) {
    constexpr int KC = (K < 512) ? K : 512;
    constexpr int LROW = KC + 8;
    const int tid = threadIdx.x, w = tid >> 6, l = tid & 63;
    const int fr = l & 15, fq = l >> 4;
    const int fbase = (vb % NSLICE) * NFEAT;
    const int tok0 = (vb / NSLICE) * 128 + w * 32;

    f32x4 acc[2][NF];
    #pragma unroll
    for (int t = 0; t < 2; t++)
        #pragma unroll
        for (int f = 0; f < NF; f++)
            #pragma unroll
            for (int r = 0; r < 4; r++) acc[t][f][r] = 0.f;

    const u16* arow0 = A + (size_t)(tok0 + fr) * K;

    for (int kc = 0; kc < K; kc += KC) {
        __syncthreads();                         // previous reads (or prev vb) done
        {   // stage W[fbase..+NFEAT][kc..kc+KC] into padded LDS
            constexpr int CH = NFEAT * KC / 8;   // 16B chunks (multiple of 256)
            #pragma unroll
            for (int c0 = 0; c0 < CH; c0 += 256) {
                int c = c0 + tid;
                int row = c / (KC / 8), cp = c % (KC / 8);
                *(uint4*)&Wl[row * LROW + cp * 8] =
                    *(const uint4*)(W + (size_t)(fbase + row) * K + kc + cp * 8);
            }
        }
        __syncthreads();
        constexpr int STEPS = KC / 32;
        bf16x8 afb[2][2];
        #pragma unroll
        for (int t = 0; t < 2; t++)
            afb[0][t] = *(const bf16x8*)(arow0 + (size_t)t * 16 * K + kc + fq * 8);
        #pragma unroll 4
        for (int s = 0; s < STEPS; s++) {
            const int p = s & 1;
            if (s + 1 < STEPS) {                 // prefetch next step's A frags
                #pragma unroll
                for (int t = 0; t < 2; t++)
                    afb[p ^ 1][t] = *(const bf16x8*)(arow0 + (size_t)t * 16 * K
                                                     + kc + (s + 1) * 32 + fq * 8);
            }
            bf16x8 wf[NF];
            #pragma unroll
            for (int f = 0; f < NF; f++)
                wf[f] = *(const bf16x8*)&Wl[(f * 16 + fr) * LROW + s * 32 + fq * 8];
            #pragma unroll
            for (int t = 0; t < 2; t++)
                #pragma unroll
                for (int f = 0; f < NF; f++)
                    acc[t][f] = __builtin_amdgcn_mfma_f32_16x16x32_bf16(
                        wf[f], afb[p][t], acc[t][f], 0, 0, 0);
        }
    }

    #pragma unroll
    for (int t = 0; t < 2; t++) {
        const int tok = tok0 + t * 16 + fr;
        #pragma unroll
        for (int f = 0; f < NF; f++) {
            const int fb = fbase + f * 16 + fq * 4;
            f32x4 v = acc[t][f];
            if (EPI == 0) {
                const float qs = (fb < 256) ? QSCALE : 1.f;
                *(uint2*)(Cb + (size_t)tok * M + fb) =
                    make_uint2(pkbf(v[0]*qs, v[1]*qs), pkbf(v[2]*qs, v[3]*qs));
            } else if (EPI == 1) {
                float4 r4 = *(const float4*)(R + (size_t)tok * M + fb);
                *(float4*)(Cf + (size_t)tok * M + fb) =
                    make_float4(v[0]+r4.x, v[1]+r4.y, v[2]+r4.z, v[3]+r4.w);
            } else if (EPI == 2) {
                float4 b4 = *(const float4*)(bias + fb);
                *(uint2*)(Cb + (size_t)tok * M + fb) = make_uint2(
                    pkbf(fmaxf(v[0]+b4.x, 0.f), fmaxf(v[1]+b4.y, 0.f)),
                    pkbf(fmaxf(v[2]+b4.z, 0.f), fmaxf(v[3]+b4.w, 0.f)));
            } else {   // in-place: out = acc + bias + out
                float4 b4 = *(const float4*)(bias + fb);
                float4 r4 = *(const float4*)(Cf + (size_t)tok * M + fb);
                *(float4*)(Cf + (size_t)tok * M + fb) = make_float4(
                    v[0]+b4.x+r4.x, v[1]+b4.y+r4.y, v[2]+b4.z+r4.z, v[3]+b4.w+r4.w);
            }
        }
    }
}

// ---- attention phase: no-max softmax, kv-split, software-pipelined --------
// Round-7 geometry (best measured, 62 us standalone). vblock = (b,h) x 64 q;
// qw=w&1 picks 32-q group, kw=w>>1 picks 1024-kv half; merge = plain add.
__device__ __forceinline__ void attn_phase(u16* smem, int vb,
        const u16* __restrict__ qkv, u16* __restrict__ attn) {
    const int bh = vb & 31, b = bh >> 3, h = bh & 7;
    const int q0 = (vb >> 5) * 64;
    const int tid = threadIdx.x, w = tid >> 6, l = tid & 63;
    const int qw = w & 1, kw = w >> 1;
    const int fr = l & 15, fq = l >> 4;
    const size_t btok = (size_t)b * TS;

    u16* Vt = smem;               // [2][4*1296] = 10368 u16
    u16* Pl = smem + 10368;       // [4][1280]   = 5120 u16
    u16* Pw = Pl + w * 1280;

    bf16x8 qf[2];                 // B-operand: fr = q, fq*8.. = d (pre-scaled)
    #pragma unroll
    for (int qs = 0; qs < 2; qs++)
        qf[qs] = *(const bf16x8*)(qkv +
            (btok + q0 + qw * 32 + qs * 16 + fr) * 768 + h * 32 + fq * 8);

    f32x4 o[2][2];                // O^T: (d = ds*16+fq*4+r, q = qs*16+fr)
    #pragma unroll
    for (int ds = 0; ds < 2; ds++)
        #pragma unroll
        for (int qs = 0; qs < 2; qs++)
            #pragma unroll
            for (int r = 0; r < 4; r++) o[ds][qs][r] = 0.f;
    float ps[2] = {0.f, 0.f};

    const int vkv = l * 2, vd0 = qw * 16;
    const u16* kbase = qkv + btok * 768 + 256 + h * 32;
    const int kvbase = kw * 1024;

#define KLOAD(ci, a_, b_) { \
        const u16* krow_ = kbase + (size_t)(kvbase + (ci) * 32) * 768; \
        a_ = *(const bf16x8*)(krow_ + (size_t)fr * 768 + fq * 8); \
        b_ = *(const bf16x8*)(krow_ + (size_t)(16 + fr) * 768 + fq * 8); }

    bf16x8 kA[2], kB[2];
    f32x4 st[2][2][2];            // [parity][kv-half-of-32][qs]
    KLOAD(0, kA[0], kB[0]);
    KLOAD(1, kA[1], kB[1]);
    {
        f32x4 z; z[0] = z[1] = z[2] = z[3] = 0.f;
        #pragma unroll
        for (int qs = 0; qs < 2; qs++) {
            st[0][0][qs] = __builtin_amdgcn_mfma_f32_16x16x32_bf16(kA[0], qf[qs], z, 0, 0, 0);
            st[0][1][qs] = __builtin_amdgcn_mfma_f32_16x16x32_bf16(kB[0], qf[qs], z, 0, 0, 0);
        }
    }

    for (int it = 0; it < 8; it++) {
        const int kv0 = kvbase + it * 128;
        __syncthreads();          // Vt reuse fence (also vs previous vblock)
        {   // stage V^T for this wave-pair's kv half: 2 kv rows x 16 d / thread
            const u16* va = qkv + (btok + kv0 + vkv) * 768 + 512 + h * 32 + vd0;
            uint4 ra0 = *(const uint4*)va;
            uint4 ra1 = *(const uint4*)(va + 8);
            uint4 rb0 = *(const uint4*)(va + 768);
            uint4 rb1 = *(const uint4*)(va + 776);
            const u16* pa0 = (const u16*)&ra0; const u16* pa1 = (const u16*)&ra1;
            const u16* pb0 = (const u16*)&rb0; const u16* pb1 = (const u16*)&rb1;
            u16* vb_ = Vt + kw * 5184 + (vkv >> 5) * 1296 + (vkv & 31);
            #pragma unroll
            for (int i = 0; i < 8; i++) {
                *(u32*)&vb_[(vd0 + i) * 40]     = (u32)pa0[i] | ((u32)pb0[i] << 16);
                *(u32*)&vb_[(vd0 + 8 + i) * 40] = (u32)pa1[i] | ((u32)pb1[i] << 16);
            }
        }
        __syncthreads();
        #pragma unroll
        for (int sub = 0; sub < 4; sub++) {
            const int ci = it * 4 + sub;
            const int p = ci & 1, np = p ^ 1;
            // 1. prefetch kf for ci+2
            KLOAD((ci + 2) & 31, kA[p], kB[p]);
            // 2. exp/pack/store P for current st[p]
            #pragma unroll
            for (int qs = 0; qs < 2; qs++) {
                float p0[4], p1[4];
                #pragma unroll
                for (int r = 0; r < 4; r++) {
                    p0[r] = EXP2(st[p][0][qs][r]);
                    p1[r] = EXP2(st[p][1][qs][r]);
                }
                ps[qs] += ((p0[0]+p0[1]) + (p0[2]+p0[3]))
                        + ((p1[0]+p1[1]) + (p1[2]+p1[3]));
                u16* prow = &Pw[(qs * 16 + fr) * 40];
                *(uint2*)&prow[fq * 4]      = make_uint2(pkbf(p0[0],p0[1]), pkbf(p0[2],p0[3]));
                *(uint2*)&prow[16 + fq * 4] = make_uint2(pkbf(p1[0],p1[1]), pkbf(p1[2],p1[3]));
            }
            // 3. QK for ci+1 (overlaps P round-trip latency)
            {
                f32x4 z; z[0] = z[1] = z[2] = z[3] = 0.f;
                #pragma unroll
                for (int qs = 0; qs < 2; qs++) {
                    st[np][0][qs] = __builtin_amdgcn_mfma_f32_16x16x32_bf16(kA[np], qf[qs], z, 0, 0, 0);
                    st[np][1][qs] = __builtin_amdgcn_mfma_f32_16x16x32_bf16(kB[np], qf[qs], z, 0, 0, 0);
                }
            }
            // 4. PV: O^T += V^T * P^T
            bf16x8 pf0 = *(const bf16x8*)&Pw[fr * 40 + fq * 8];
            bf16x8 pf1 = *(const bf16x8*)&Pw[(16 + fr) * 40 + fq * 8];
            const u16* vs = Vt + kw * 5184 + sub * 1296;
            bf16x8 vf0 = *(const bf16x8*)&vs[fr * 40 + fq * 8];
            bf16x8 vf1 = *(const bf16x8*)&vs[(16 + fr) * 40 + fq * 8];
            o[0][0] = __builtin_amdgcn_mfma_f32_16x16x32_bf16(vf0, pf0, o[0][0], 0, 0, 0);
            o[0][1] = __builtin_amdgcn_mfma_f32_16x16x32_bf16(vf0, pf1, o[0][1], 0, 0, 0);
            o[1][0] = __builtin_amdgcn_mfma_f32_16x16x32_bf16(vf1, pf0, o[1][0], 0, 0, 0);
            o[1][1] = __builtin_amdgcn_mfma_f32_16x16x32_bf16(vf1, pf1, o[1][1], 0, 0, 0);
        }
    }
    // reduce ps across fq within each wave
    #pragma unroll
    for (int qs = 0; qs < 2; qs++) {
        ps[qs] += __shfl_xor(ps[qs], 16, 64);
        ps[qs] += __shfl_xor(ps[qs], 32, 64);
    }
    // merge kv halves: kw=1 dumps (o, ps); kw=0 adds + stores
    __syncthreads();
    float* mrg = (float*)smem;    // 128 lanes x 18 floats = 9216 B
    if (kw == 1) {
        float* p = mrg + (qw * 64 + l) * 18;
        #pragma unroll
        for (int ds = 0; ds < 2; ds++)
            #pragma unroll
            for (int qs = 0; qs < 2; qs++)
                #pragma unroll
                for (int r = 0; r < 4; r++) p[ds * 8 + qs * 4 + r] = o[ds][qs][r];
        p[16] = ps[0]; p[17] = ps[1];
    }
    __syncthreads();
    if (kw == 0) {
        const float* p = mrg + (qw * 64 + l) * 18;
        #pragma unroll
        for (int ds = 0; ds < 2; ds++)
            #pragma unroll
            for (int qs = 0; qs < 2; qs++)
                #pragma unroll
                for (int r = 0; r < 4; r++) o[ds][qs][r] += p[ds * 8 + qs * 4 + r];
        ps[0] += p[16]; ps[1] += p[17];
        #pragma unroll
        for (int qs = 0; qs < 2; qs++) {
            float inv = 1.f / ps[qs];
            int tok = (int)btok + q0 + qw * 32 + qs * 16 + fr;
            #pragma unroll
            for (int ds = 0; ds < 2; ds++) {
                *(uint2*)(attn + (size_t)tok * 256 + h * 32 + ds * 16 + fq * 4) =
                    make_uint2(pkbf(o[ds][qs][0]*inv, o[ds][qs][1]*inv),
                               pkbf(o[ds][qs][2]*inv, o[ds][qs][3]*inv));
            }
        }
    }
#undef KLOAD
}

// --------- persistent megakernel: 7 phases, hand-rolled grid barrier -------
// 512 blocks = 2 blocks/CU guaranteed (LDS 33.8 KB x 2 = 67.6 KB < 160 KB;
// launch_bounds(256,2) caps VGPR at 256). Plain launch -> graph-capturable.
__global__ __launch_bounds__(256, 2) void mega(
        const float* __restrict__ src, const float* __restrict__ w_in,
        const float* __restrict__ w_out, const float* __restrict__ w1,
        const float* __restrict__ b1, const float* __restrict__ w2,
        const float* __restrict__ b2, const float* __restrict__ g1,
        const float* __restrict__ be1, const float* __restrict__ g2,
        const float* __restrict__ be2, float* __restrict__ out,
        u16* xb, u16* qkvb, u16* x2b, u16* wib, u16* wob, u16* w1b, u16* w2b,
        u32* bar) {
    __shared__ __align__(16) u16 smem[16896];    // 33792 B (max over phases)
    const int bid = blockIdx.x;
    u32* cnt = bar;
    u32* gen = bar + 16;                         // separate cache lines

    // ph0: LN1 (vb 0..1023) + weight convert (vb 1024..1791)
    for (int vb = bid; vb < 1792; vb += NBLK) {
        if (vb < 1024) ln_phase(vb, src, xb, g1, be1);
        else conv_phase(vb - 1024, w_in, wib, w_out, wob, w1, w1b, w2, w2b);
    }
    gsync(cnt, gen);
    // ph1: qkvb = xb @ w_in^T (q pre-scaled); 12 slices x 64 tokgrps = 768 vb
    for (int vb = bid; vb < 768; vb += NBLK)
        wgemm_phase<256, 64, 4, 12, 0>(smem, vb, xb, wib, nullptr, nullptr,
                                       nullptr, qkvb, 768);
    gsync(cnt, gen);
    // ph2: attention -> attnb (= xb, dead after ph1); 1024 vb
    for (int vb = bid; vb < 1024; vb += NBLK)
        attn_phase(smem, vb, qkvb, xb);
    gsync(cnt, gen);
    // ph3: out = src + attnb @ w_out^T; 8 slices x 64 tokgrps = 512 vb
    wgemm_phase<256, 32, 2, 8, 1>(smem, bid, xb, wob, nullptr, src,
                                  out, nullptr, 256);
    gsync(cnt, gen);
    // ph4: x2b = LN2(out); 1024 vb
    for (int vb = bid; vb < 1024; vb += NBLK)
        ln_phase(vb, out, x2b, g2, be2);
    gsync(cnt, gen);
    // ph5: h1b (= xb region, 16 MB) = relu(x2b @ w1^T + b1); 16 x 64 = 1024 vb
    for (int vb = bid; vb < 1024; vb += NBLK)
        wgemm_phase<256, 64, 4, 16, 2>(smem, vb, x2b, w1b, b1, nullptr,
                                       nullptr, xb, 1024);
    gsync(cnt, gen);
    // ph6: out = out + h1b @ w2^T + b2 (K=1024, 2-chunk W staging); 512 vb
    wgemm_phase<1024, 32, 2, 8, 3>(smem, bid, xb, w2b, b2, nullptr,
                                   out, nullptr, 256);
}

extern "C" void kernel_launch(void* const* d_in, const int* in_sizes, int n_in,
                              void* d_out, int out_size, void* d_ws, size_t ws_size,
                              hipStream_t stream) {
    const float* src  = (const float*)d_in[0];
    const float* w_in = (const float*)d_in[1];
    const float* w_out= (const float*)d_in[2];
    const float* w1   = (const float*)d_in[3];
    const float* b1   = (const float*)d_in[4];
    const float* w2   = (const float*)d_in[5];
    const float* b2   = (const float*)d_in[6];
    const float* g1   = (const float*)d_in[7];
    const float* be1  = (const float*)d_in[8];
    const float* g2   = (const float*)d_in[9];
    const float* be2  = (const float*)d_in[10];
    float* out = (float*)d_out;

    u16* xb    = (u16*)d_ws;                       // 8192*256 (attnb/h1b reuse)
    u16* qkvb  = xb + (size_t)NTOK * 256;          // 8192*768
    u16* x2b   = (u16*)((char*)d_ws + (size_t)NTOK * 1024 * 2);
    u16* wib   = x2b + (size_t)NTOK * 256;
    u16* wob   = wib + 768 * 256;
    u16* w1b   = wob + 256 * 256;
    u16* w2b   = w1b + 1024 * 256;
    u32* bar   = (u32*)(w2b + 1024 * 256);         // 128 B barrier state @ ~22.5 MB

    hipMemsetAsync(bar, 0, 128, stream);           // zero cnt/gen every call
    mega<<<NBLK, 256, 0, stream>>>(src, w_in, w_out, w1, b1, w2, b2,
                                   g1, be1, g2, be2, out,
                                   xb, qkvb, x2b, wib, wob, w1b, w2b, bar);
}